// Round 3
// baseline (278.748 us; speedup 1.0000x reference)
//
#include <hip/hip_runtime.h>
#include <cmath>

// Shapes fixed by the reference: data [32,128,80,80] int32, scale 0.0625.
#define NB  32
#define NC  128
#define NHW 6400          // 80*80, contiguous per (b,c)
#define TPB 64            // ONE wave per block: fully autonomous, no convoy

typedef float vfloat4 __attribute__((ext_vector_type(4)));

// ---------------------------------------------------------------------------
// Setup kernel: build the two 256-entry LUTs once into d_ws.
// EXACT math of the verified in-block LUT builder (do not touch).
// 4 blocks x 64 threads; entry index = blockIdx*64 + tid.
// ---------------------------------------------------------------------------
__global__ __launch_bounds__(64) void lut_build_kernel(
    int* __restrict__ exp_ws, float* __restrict__ rec_ws,
    const float* __restrict__ dscale) {
#pragma clang fp contract(off)
  const int t = blockIdx.x * 64 + threadIdx.x;   // 0..255
  const float ds = dscale[0];

  const float EXP_SCALE_F = (float)(2.0 / 65535.0);
  float x = (float)(-t) * ds;
  float e;
  if (x >= 0.0f) {
    float y0 = expf(0.0f), y1 = expf(1.0f);
    e = rintf((y0 + x * ((y1 - y0) / 1.0f)) / EXP_SCALE_F);
  } else if (x >= -10.0f) {
    float delta = 10.0f / 255.0f;
    float idxf = rintf((x + 10.0f) * 25.5f);
    idxf = fminf(fmaxf(idxf, 0.0f), 255.0f);
    float xs = -10.0f + idxf * delta;
    e = rintf((float)exp((double)xs) / EXP_SCALE_F);
  } else {
    float delta = 10.0f / 255.0f;
    float idxf = rintf((x + 20.0f) * 25.5f);
    idxf = fminf(fmaxf(idxf, 0.0f), 255.0f);
    float xs = -20.0f + idxf * delta;
    e = rintf((float)exp((double)xs) / EXP_SCALE_F);
  }
  e = fminf(fmaxf(e, -32768.0f), 32767.0f);
  exp_ws[t] = (int)e;

  const float RECIP_SCALE_F = (float)((1.0 / 0.1) * 2.0 / 65535.0);
  float deltar = (250.0f - 0.1f) / 255.0f;
  float xs = 0.1f + (float)t * deltar;
  float r = rintf((1.0f / xs) / RECIP_SCALE_F);
  r = fminf(fmaxf(r, -32768.0f), 32767.0f);
  rec_ws[t] = r;
}

// ---------------------------------------------------------------------------
// Main kernel. Wave-autonomous: lane = cg*16 + p4.
//   cg = lane>>4 (0..3): owns channels {cg, cg+4, ..., cg+124}  (32 channels)
//   p4 = lane&15      : owns pixels {4*p4 .. 4*p4+3}            (one int4)
// 16 consecutive lanes (fixed cg) cover 256 B contiguous per channel row ->
// full-line loads/stores (round-1 lesson). Channel reductions are wave-local:
// __shfl_xor over lane bits 4,5 (2 steps), exact int max/add -> NO inter-wave
// barriers, waves desynchronize and keep the memory pipe continuously fed.
// ---------------------------------------------------------------------------
__global__ __launch_bounds__(TPB, 4) void qsoftmax_kernel(
    const int* __restrict__ data,
    const int* __restrict__ exp_ws,
    const float* __restrict__ rec_ws,
    float* __restrict__ out) {
#pragma clang fp contract(off)
  __shared__ int   exp_tab[256];    // quantized exp as function of j = qmax - data
  __shared__ float recip_tab[256];  // quantized 1/v table, region (0.1, 250)

  const int t  = threadIdx.x;       // 0..63
  const int cg = t >> 4;            // channel group 0..3
  const int p4 = t & 15;            // pixel quad 0..15

  const int blk  = blockIdx.x;              // 0..3199, one 64-pixel tile
  const int b    = blk / (NHW / 64);
  const int hw0  = (blk % (NHW / 64)) * 64;
  const int base4 = b * NC * (NHW / 4) + (hw0 >> 2) + p4;   // int4 index

  // ---- stage LUTs from global (built by lut_build_kernel) ----
  {
    int4   ev = ((const int4*)exp_ws)[t];      // entries 4t..4t+3
    float4 rv = ((const float4*)rec_ws)[t];
    ((int4*)exp_tab)[t]     = ev;
    ((float4*)recip_tab)[t] = rv;
  }

  // ---- load 32 channels x 4 pixels; pack to 4x int8 per int; local max ----
  const int4* g4 = (const int4*)data;
  int pd[32];                        // packed raw data
  int4 m = make_int4(-128, -128, -128, -128);
#pragma unroll
  for (int i = 0; i < 32; ++i) {
    int4 v = g4[base4 + (4 * i + cg) * (NHW / 4)];
    m.x = max(m.x, v.x); m.y = max(m.y, v.y);
    m.z = max(m.z, v.z); m.w = max(m.w, v.w);
    pd[i] = (v.x & 255) | ((v.y & 255) << 8) | ((v.z & 255) << 16) |
            (int)((unsigned)(v.w & 255) << 24);
  }

  // ---- wave all-reduce max over cg (lane bits 4,5); exact int max ----
#pragma unroll
  for (int xm = 16; xm <= 32; xm <<= 1) {
    m.x = max(m.x, __shfl_xor(m.x, xm, 64));
    m.y = max(m.y, __shfl_xor(m.y, xm, 64));
    m.z = max(m.z, __shfl_xor(m.z, xm, 64));
    m.w = max(m.w, __shfl_xor(m.w, xm, 64));
  }

  // LDS visibility of the LUT writes before the random gathers (single-wave
  // block: this is cheap; also stops IR-level reordering of read before write).
  __syncthreads();

  // ---- exp LUT gather + pack exp (u16 pairs) + channel partial sum ----
  int pe[64];                        // packed exp, 2 pixels per int
  int4 s = make_int4(0, 0, 0, 0);
#pragma unroll
  for (int i = 0; i < 32; ++i) {
    int pdv = pd[i];
    int c0 = (pdv << 24) >> 24;
    int c1 = (pdv << 16) >> 24;
    int c2 = (pdv << 8) >> 24;
    int c3 = pdv >> 24;
    int e0 = exp_tab[m.x - c0];      // j guaranteed in [0,255]
    int e1 = exp_tab[m.y - c1];
    int e2 = exp_tab[m.z - c2];
    int e3 = exp_tab[m.w - c3];
    s.x += e0; s.y += e1; s.z += e2; s.w += e3;
    pe[2 * i]     = e0 | (e1 << 16); // e in [0,32767] -> fits u16, sign-safe
    pe[2 * i + 1] = e2 | (e3 << 16);
  }

  // ---- wave all-reduce sum over cg (lane bits 4,5); exact int add ----
#pragma unroll
  for (int xm = 16; xm <= 32; xm <<= 1) {
    s.x += __shfl_xor(s.x, xm, 64);
    s.y += __shfl_xor(s.y, xm, 64);
    s.z += __shfl_xor(s.z, xm, 64);
    s.w += __shfl_xor(s.w, xm, 64);
  }

  // ---- per-lane recip (redundant across cg lanes; identical values) ----
  const float DIV_SCALE_F = (float)((2.0 / 65535.0) * 128.0); // exp_scale * 2^7
  const float RIDX_K_F    = (float)(255.0 / (250.0 - 0.1));
  float rq[4];
  {
    int tv[4] = {s.x, s.y, s.z, s.w};
#pragma unroll
    for (int j = 0; j < 4; ++j) {
      float ss = rintf((float)tv[j] * 0.0078125f);
      ss = fminf(fmaxf(ss, -32768.0f), 32767.0f);
      float v = ss * DIV_SCALE_F;
      float idxf = rintf((v - 0.1f) * RIDX_K_F);
      idxf = fminf(fmaxf(idxf, 0.0f), 255.0f);
      rq[j] = recip_tab[(int)idxf];
    }
  }

  // ---- epilogue: out = clip(round((e*r)*K), -128, 127) * OUT_SCALE ----
  const float K_F = (float)((2.0 / 65535.0) * ((1.0 / 0.1) * 2.0 / 65535.0) / (2.0 / 255.0));
  const float OUT_SCALE_F = (float)(2.0 / 255.0);
  vfloat4* o4 = (vfloat4*)out;
#pragma unroll
  for (int i = 0; i < 32; ++i) {
    int pa = pe[2 * i], pb = pe[2 * i + 1];
    float e0 = (float)(pa & 0xFFFF);
    float e1 = (float)(pa >> 16);
    float e2 = (float)(pb & 0xFFFF);
    float e3 = (float)(pb >> 16);
    vfloat4 o;
    o.x = fminf(fmaxf(rintf((e0 * rq[0]) * K_F), -128.0f), 127.0f) * OUT_SCALE_F;
    o.y = fminf(fmaxf(rintf((e1 * rq[1]) * K_F), -128.0f), 127.0f) * OUT_SCALE_F;
    o.z = fminf(fmaxf(rintf((e2 * rq[2]) * K_F), -128.0f), 127.0f) * OUT_SCALE_F;
    o.w = fminf(fmaxf(rintf((e3 * rq[3]) * K_F), -128.0f), 127.0f) * OUT_SCALE_F;
    __builtin_nontemporal_store(o, &o4[base4 + (4 * i + cg) * (NHW / 4)]);
  }
}

extern "C" void kernel_launch(void* const* d_in, const int* in_sizes, int n_in,
                              void* d_out, int out_size, void* d_ws, size_t ws_size,
                              hipStream_t stream) {
  const int* data     = (const int*)d_in[0];
  const float* dscale = (const float*)d_in[1];
  float* out          = (float*)d_out;
  (void)in_sizes; (void)n_in; (void)out_size; (void)ws_size;

  int*   exp_ws = (int*)d_ws;                       // 256 x int
  float* rec_ws = (float*)((char*)d_ws + 1024);     // 256 x float

  lut_build_kernel<<<dim3(4), dim3(64), 0, stream>>>(exp_ws, rec_ws, dscale);
  qsoftmax_kernel<<<dim3(NB * (NHW / 64)), dim3(TPB), 0, stream>>>(
      data, exp_ws, rec_ws, out);
}

// Round 4
// 186.566 us; speedup vs baseline: 1.4941x; 1.4941x over previous
//
#include <hip/hip_runtime.h>
#include <cmath>

// Shapes fixed by the reference: data [32,128,80,80] int32, scale 0.0625.
#define NB  32
#define NC  128
#define NHW 6400          // 80*80, contiguous per (b,c)
#define TPB 256           // 16 "k" channel-groups x 16 pixel-quads (champion map)
// Each block: TWO 64-pixel tiles (A at hw0, B at hw0+64), grid 1600.

typedef float vfloat4 __attribute__((ext_vector_type(4)));

// Raw barrier: publish LDS writes (lgkmcnt only) WITHOUT draining vmcnt, so
// tile-B's prefetched global loads stay in flight across reduction barriers.
// (m201-verified idiom; __syncthreads would emit s_waitcnt vmcnt(0).)
#define LDS_BARRIER()                                        \
  do {                                                       \
    asm volatile("s_waitcnt lgkmcnt(0)" ::: "memory");       \
    __builtin_amdgcn_s_barrier();                            \
    asm volatile("" ::: "memory");                           \
  } while (0)

// One tile of the champion pipeline. PAR selects the LDS parity buffers,
// V is the 8-entry int4 register array (already-issued loads), BASE4T the
// int4 base index of the tile. Expands inline; all indices compile-time.
#define PROCESS_TILE(PAR, V, BASE4T)                                           \
  do {                                                                         \
    int pd[8];                                                                 \
    int4 m = make_int4(-128, -128, -128, -128);                                \
    _Pragma("unroll")                                                          \
    for (int i = 0; i < 8; ++i) {                                              \
      int4 v = (V)[i];                                                         \
      m.x = max(m.x, v.x); m.y = max(m.y, v.y);                                \
      m.z = max(m.z, v.z); m.w = max(m.w, v.w);                                \
      pd[i] = (v.x & 255) | ((v.y & 255) << 8) | ((v.z & 255) << 16) |         \
              (int)((unsigned)(v.w & 255) << 24);                              \
    }                                                                          \
    red_m[PAR][k][p4] = m;                                                     \
    LDS_BARRIER();                                                             \
    int4 q = red_m[PAR][0][p4];                                                \
    _Pragma("unroll")                                                          \
    for (int kk = 1; kk < 16; ++kk) {                                          \
      int4 r = red_m[PAR][kk][p4];                                             \
      q.x = max(q.x, r.x); q.y = max(q.y, r.y);                                \
      q.z = max(q.z, r.z); q.w = max(q.w, r.w);                                \
    }                                                                          \
    int pe[16];                                                                \
    int4 s = make_int4(0, 0, 0, 0);                                            \
    _Pragma("unroll")                                                          \
    for (int i = 0; i < 8; ++i) {                                              \
      int pdv = pd[i];                                                         \
      int c0 = (pdv << 24) >> 24;                                              \
      int c1 = (pdv << 16) >> 24;                                              \
      int c2 = (pdv << 8) >> 24;                                               \
      int c3 = pdv >> 24;                                                      \
      int e0 = exp_tab[q.x - c0];      /* j guaranteed in [0,255] */           \
      int e1 = exp_tab[q.y - c1];                                              \
      int e2 = exp_tab[q.z - c2];                                              \
      int e3 = exp_tab[q.w - c3];                                              \
      s.x += e0; s.y += e1; s.z += e2; s.w += e3;                              \
      pe[2 * i]     = e0 | (e1 << 16);                                         \
      pe[2 * i + 1] = e2 | (e3 << 16);                                         \
    }                                                                          \
    red_s[PAR][k][p4] = s;                                                     \
    LDS_BARRIER();                                                             \
    int4 tot = red_s[PAR][0][p4];                                              \
    _Pragma("unroll")                                                          \
    for (int kk = 1; kk < 16; ++kk) {                                          \
      int4 r = red_s[PAR][kk][p4];                                             \
      tot.x += r.x; tot.y += r.y; tot.z += r.z; tot.w += r.w;                  \
    }                                                                          \
    float rq[4];                                                               \
    {                                                                          \
      int tv[4] = {tot.x, tot.y, tot.z, tot.w};                                \
      _Pragma("unroll")                                                        \
      for (int j = 0; j < 4; ++j) {                                            \
        float ss = rintf((float)tv[j] * 0.0078125f);                           \
        ss = fminf(fmaxf(ss, -32768.0f), 32767.0f);                            \
        float vv = ss * DIV_SCALE_F;                                           \
        float idxf = rintf((vv - 0.1f) * RIDX_K_F);                            \
        idxf = fminf(fmaxf(idxf, 0.0f), 255.0f);                               \
        rq[j] = recip_tab[(int)idxf];                                          \
      }                                                                        \
    }                                                                          \
    _Pragma("unroll")                                                          \
    for (int i = 0; i < 8; ++i) {                                              \
      int pa = pe[2 * i], pb = pe[2 * i + 1];                                  \
      float e0 = (float)(pa & 0xFFFF);                                         \
      float e1 = (float)(pa >> 16);                                            \
      float e2 = (float)(pb & 0xFFFF);                                         \
      float e3 = (float)(pb >> 16);                                            \
      vfloat4 o;                                                               \
      o.x = fminf(fmaxf(rintf((e0 * rq[0]) * K_F), -128.0f), 127.0f) * OUT_SCALE_F; \
      o.y = fminf(fmaxf(rintf((e1 * rq[1]) * K_F), -128.0f), 127.0f) * OUT_SCALE_F; \
      o.z = fminf(fmaxf(rintf((e2 * rq[2]) * K_F), -128.0f), 127.0f) * OUT_SCALE_F; \
      o.w = fminf(fmaxf(rintf((e3 * rq[3]) * K_F), -128.0f), 127.0f) * OUT_SCALE_F; \
      __builtin_nontemporal_store(o, &o4[(BASE4T) + (16 * i + k) * (NHW / 4) + p4]); \
    }                                                                          \
  } while (0)

__global__ __launch_bounds__(TPB, 4) void qsoftmax_kernel(
    const int* __restrict__ data,
    const float* __restrict__ dscale,
    float* __restrict__ out) {
#pragma clang fp contract(off)
  __shared__ int   exp_tab[256];      // quantized exp, j = qmax - data
  __shared__ float recip_tab[256];    // quantized 1/v table, region (0.1, 250)
  __shared__ int4  red_m[2][16][16];  // [tile parity][k][p4] partial max
  __shared__ int4  red_s[2][16][16];  // [tile parity][k][p4] partial sum

  const int t  = threadIdx.x;
  const int k  = t >> 4;
  const int p4 = t & 15;

  const int blk  = blockIdx.x;                 // 0..1599
  const int b    = blk / (NHW / 128);          // /50
  const int hw0  = (blk % (NHW / 128)) * 128;  // 128 pixels per block
  const int base4 = b * NC * (NHW / 4) + (hw0 >> 2);   // tile A; tile B = +16

  const float ds = dscale[0];  // 0.0625

  // ---- issue ALL global loads first (tiles A and B), before any barrier ----
  const int4* g4 = (const int4*)data;
  int4 vA[8], vB[8];
#pragma unroll
  for (int i = 0; i < 8; ++i)
    vA[i] = g4[base4 + (16 * i + k) * (NHW / 4) + p4];
#pragma unroll
  for (int i = 0; i < 8; ++i)
    vB[i] = g4[base4 + 16 + (16 * i + k) * (NHW / 4) + p4];

  // ---- build LUTs (identical math to the verified version; do not touch) ----
  {
    const float EXP_SCALE_F = (float)(2.0 / 65535.0);
    float x = (float)(-t) * ds;
    float e;
    if (x >= 0.0f) {
      float y0 = expf(0.0f), y1 = expf(1.0f);
      e = rintf((y0 + x * ((y1 - y0) / 1.0f)) / EXP_SCALE_F);
    } else if (x >= -10.0f) {
      float delta = 10.0f / 255.0f;
      float idxf = rintf((x + 10.0f) * 25.5f);
      idxf = fminf(fmaxf(idxf, 0.0f), 255.0f);
      float xs = -10.0f + idxf * delta;
      e = rintf((float)exp((double)xs) / EXP_SCALE_F);
    } else {
      float delta = 10.0f / 255.0f;
      float idxf = rintf((x + 20.0f) * 25.5f);
      idxf = fminf(fmaxf(idxf, 0.0f), 255.0f);
      float xs = -20.0f + idxf * delta;
      e = rintf((float)exp((double)xs) / EXP_SCALE_F);
    }
    e = fminf(fmaxf(e, -32768.0f), 32767.0f);
    exp_tab[t] = (int)e;

    const float RECIP_SCALE_F = (float)((1.0 / 0.1) * 2.0 / 65535.0);
    float deltar = (250.0f - 0.1f) / 255.0f;
    float xs = 0.1f + (float)t * deltar;
    float r = rintf((1.0f / xs) / RECIP_SCALE_F);
    r = fminf(fmaxf(r, -32768.0f), 32767.0f);
    recip_tab[t] = r;
  }
  LDS_BARRIER();   // publish LUTs; vA/vB loads remain in flight (no vmcnt drain)

  const float DIV_SCALE_F  = (float)((2.0 / 65535.0) * 128.0); // exp_scale * 2^7
  const float RIDX_K_F     = (float)(255.0 / (250.0 - 0.1));
  const float K_F          = (float)((2.0 / 65535.0) * ((1.0 / 0.1) * 2.0 / 65535.0) / (2.0 / 255.0));
  const float OUT_SCALE_F  = (float)(2.0 / 255.0);
  vfloat4* o4 = (vfloat4*)out;

  // ---- tile A (consumes vA; vB still in flight, hidden under A's compute) --
  PROCESS_TILE(0, vA, base4);
  // ---- tile B (loads issued one full tile ago -> latency fully hidden) ----
  PROCESS_TILE(1, vB, base4 + 16);
}

extern "C" void kernel_launch(void* const* d_in, const int* in_sizes, int n_in,
                              void* d_out, int out_size, void* d_ws, size_t ws_size,
                              hipStream_t stream) {
  const int* data     = (const int*)d_in[0];
  const float* dscale = (const float*)d_in[1];
  float* out          = (float*)d_out;
  (void)in_sizes; (void)n_in; (void)d_ws; (void)ws_size; (void)out_size;

  dim3 grid(NB * (NHW / 128));   // 32 * 50 = 1600 blocks, 2 tiles each
  qsoftmax_kernel<<<grid, TPB, 0, stream>>>(data, dscale, out);
}